// Round 1
// baseline (76.517 us; speedup 1.0000x reference)
//
#include <hip/hip_runtime.h>
#include <hip/hip_bf16.h>

#define NB 32
#define NC 128
#define NW 128
#define NH 128
#define BCH (NB * NC * NH)
#define CPB 4   // channels (= waves) per 256-thread block

// Wave-synchronous phase separator: compiler scheduling fence + LDS drain.
// Cross-lane LDS write->read within ONE wave is ordered by the hardware
// (DS ops issue in order per wave); the asm "memory" clobber stops the
// compiler from reordering LDS ops across the phase boundary.
#define WAVE_SYNC() do { __builtin_amdgcn_wave_barrier(); \
    asm volatile("s_waitcnt lgkmcnt(0)" ::: "memory"); } while (0)

static __device__ __forceinline__ float b2f(unsigned short u) {
    return __uint_as_float(((unsigned int)u) << 16);
}
static __device__ __forceinline__ unsigned short f2b(float f) {
    __hip_bfloat16 h = __float2bfloat16(f);
    return *reinterpret_cast<unsigned short*>(&h);
}

// One WAVE per (b,c) channel; 4 channels per block; no __syncthreads().
// Staging: lane owns w = {2l, 2l+1}; counting-sort by bucket floor(d) into
// tile[wid] (sorted (sA2, sA2*d, m, m*x)). Compute: lane owns h = {2l, 2l+1};
// ONE pass over the UNION window feeds BOTH h accumulations per ds_read.
//
// Math (base 2): sA2 = sqrt(softplus(k)*log2e); t' = fma(-sA2, rh, sA2*d);
//   g1 = exp2(mn - t'^2); g2 = g1^10; y = a1/s1;
//   w_out = (log2(s1) - mn)*ln2; y_t = a2/s2.
// Cutoff (per h): R = sqrt(mn_probe + 12)/sA2_min, so every dropped term is
// < m*2^-12 of the peak (probe-ring min >= true min argument bound).
__global__ __launch_bounds__(256, 4) void sci_kernel(
    const void* __restrict__ xp, const void* __restrict__ dp,
    const void* __restrict__ mp, const void* __restrict__ kp,
    void* __restrict__ outp)
{
    const int wid  = threadIdx.x >> 6;     // wave id = channel slot in block
    const int lane = threadIdx.x & 63;
    const int bc   = blockIdx.x * CPB + wid;

    __shared__ int    cnt[CPB][NW];        // histogram (per-wave private)
    __shared__ int    cum[CPB][NW + 1];    // exclusive bucket offsets
    __shared__ float4 tile[CPB][NW];       // sorted (sA2, sA2*d, m, m*x)

    // ---- dtype detection (uniform, deterministic; identical to proven ver) ----
    const unsigned short* du16 = (const unsigned short*)dp;
    bool is_bf16 = true;
    #pragma unroll
    for (int i = 0; i < 32; i += 2) {
        float v = __uint_as_float(((unsigned int)du16[i]) << 16);
        is_bf16 = is_bf16 && (v >= 0.0f) && (v <= 129.0f);
    }

    // ---- load pair w = {2l, 2l+1} (vectorized) ----
    const int w0   = lane * 2;
    const int base = bc * NW + w0;
    float dv0, mv0, xv0, kv0, dv1, mv1, xv1, kv1;
    if (is_bf16) {
        ushort2 dd = *(const ushort2*)((const unsigned short*)dp + base);
        ushort2 mm = *(const ushort2*)((const unsigned short*)mp + base);
        ushort2 xx = *(const ushort2*)((const unsigned short*)xp + base);
        ushort2 kk = *(const ushort2*)((const unsigned short*)kp + w0);
        dv0 = b2f(dd.x); dv1 = b2f(dd.y);
        mv0 = b2f(mm.x); mv1 = b2f(mm.y);
        xv0 = b2f(xx.x); xv1 = b2f(xx.y);
        kv0 = b2f(kk.x); kv1 = b2f(kk.y);
    } else {
        float2 dd = *(const float2*)((const float*)dp + base);
        float2 mm = *(const float2*)((const float*)mp + base);
        float2 xx = *(const float2*)((const float*)xp + base);
        float2 kk = *(const float2*)((const float*)kp + w0);
        dv0 = dd.x; dv1 = dd.y; mv0 = mm.x; mv1 = mm.y;
        xv0 = xx.x; xv1 = xx.y; kv0 = kk.x; kv1 = kk.y;
    }

    const float LOG2E = 1.4426950408889634f;
    // softplus(k)*log2e = log2(1 + e^k): 2 HW trans ops each
    float ex0 = __builtin_amdgcn_exp2f(kv0 * LOG2E);
    float ex1 = __builtin_amdgcn_exp2f(kv1 * LOG2E);
    float A20 = __builtin_amdgcn_logf(1.0f + ex0);   // v_log_f32 = log2
    float A21 = __builtin_amdgcn_logf(1.0f + ex1);
    float sA20 = sqrtf(A20), sA21 = sqrtf(A21);

    // ---- wave-wide min of sA2 (pure shuffle butterfly, no LDS) ----
    float rmn = fminf(sA20, sA21);
    #pragma unroll
    for (int o = 32; o >= 1; o >>= 1) rmn = fminf(rmn, __shfl_xor(rmn, o));
    const float rs = 1.0005f / rmn;        // 1/sA2_min with guard

    // ---- counting sort by bucket floor(d), wave-private ----
    cnt[wid][w0] = 0; cnt[wid][w0 + 1] = 0;
    WAVE_SYNC();
    int b0i = min(127, max(0, (int)dv0));
    int b1i = min(127, max(0, (int)dv1));
    int s0i = atomicAdd(&cnt[wid][b0i], 1);
    int s1i = atomicAdd(&cnt[wid][b1i], 1);
    WAVE_SYNC();
    int c0 = cnt[wid][w0], c1 = cnt[wid][w0 + 1];
    int p = c0 + c1, P = p;
    #pragma unroll
    for (int o = 1; o < 64; o <<= 1) {     // inclusive wave scan of bin-pairs
        int n = __shfl_up(P, o);
        if (lane >= o) P += n;
    }
    int E0 = P - p;                        // exclusive offset of bin 2l
    cum[wid][w0]     = E0;
    cum[wid][w0 + 1] = E0 + c0;
    if (lane == 63) cum[wid][NW] = NW;
    WAVE_SYNC();
    int pos0 = cum[wid][b0i] + s0i;
    int pos1 = cum[wid][b1i] + s1i;
    tile[wid][pos0] = make_float4(sA20, sA20 * dv0, mv0, mv0 * xv0);
    tile[wid][pos1] = make_float4(sA21, sA21 * dv1, mv1, mv1 * xv1);
    WAVE_SYNC();

    // ================= compute: lane owns h = {2l, 2l+1} =================
    const float STEP = 128.0f / 127.0f;
    const float rh0 = (float)w0 * STEP;
    const float rh1 = rh0 + STEP;

    float mn0 = 1e30f, s10 = 0.f, a10 = 0.f, s20 = 0.f, a20 = 0.f;
    float mn1 = 1e30f, s11 = 0.f, a11 = 0.f, s21 = 0.f, a21 = 0.f;

    const float4* T  = tile[wid];
    const int*    CU = cum[wid];

    auto body = [&](int k) {
        float4 q = T[k];
        float t0 = __builtin_fmaf(-q.x, rh0, q.y);
        float t1 = __builtin_fmaf(-q.x, rh1, q.y);
        float u0 = t0 * t0, u1 = t1 * t1;
        if (u0 < mn0) {                    // rare rescale (first hit: f=0)
            float f = __builtin_amdgcn_exp2f(u0 - mn0);
            float fs = f * f, f4 = fs * fs, f8 = f4 * f4, f10 = f8 * fs;
            s10 *= f; a10 *= f; s20 *= f10; a20 *= f10; mn0 = u0;
        }
        if (u1 < mn1) {
            float f = __builtin_amdgcn_exp2f(u1 - mn1);
            float fs = f * f, f4 = fs * fs, f8 = f4 * f4, f10 = f8 * fs;
            s11 *= f; a11 *= f; s21 *= f10; a21 *= f10; mn1 = u1;
        }
        float g0 = __builtin_amdgcn_exp2f(mn0 - u0);
        float g1 = __builtin_amdgcn_exp2f(mn1 - u1);
        float q0 = g0 * g0, p40 = q0 * q0, p80 = p40 * p40, G0 = p80 * q0;
        float q1 = g1 * g1, p41 = q1 * q1, p81 = p41 * p41, G1 = p81 * q1;
        s10 = __builtin_fmaf(q.z, g0, s10); a10 = __builtin_fmaf(q.w, g0, a10);
        s20 = __builtin_fmaf(q.z, G0, s20); a20 = __builtin_fmaf(q.w, G0, a20);
        s11 = __builtin_fmaf(q.z, g1, s11); a11 = __builtin_fmaf(q.w, g1, a11);
        s21 = __builtin_fmaf(q.z, G1, s21); a21 = __builtin_fmaf(q.w, G1, a21);
    };

    // probe ring around floor(rh0) (covers both rh's), expanded until non-empty
    int bctr = min(127, (int)rh0);
    int lo0, hi0, ps, pe;
    {
        int r = 2;
        for (;;) {
            lo0 = max(0, bctr - r); hi0 = min(127, bctr + r);
            ps = CU[lo0]; pe = CU[hi0 + 1];
            if (ps != pe) break;
            ++r;
        }
    }
    for (int k = ps; k < pe; ++k) body(k);

    // residual union window (cutoff 2^-12 for BOTH h's)
    float Rh0 = sqrtf(mn0 + 12.0f) * rs;
    float Rh1 = sqrtf(mn1 + 12.0f) * rs;
    float Lf = fminf(rh0 - Rh0, rh1 - Rh1);
    float Hf = fmaxf(rh0 + Rh0, rh1 + Rh1);
    int lo = min(lo0, max(0, (int)Lf));
    int hi = max(hi0, min(127, (int)Hf));
    int ks = CU[lo], ke = CU[hi + 1];
    for (int k = ks; k < ps; ++k) body(k);
    for (int k = pe; k < ke; ++k) body(k);

    // ---- epilogue (paired, coalesced) ----
    const float LN2 = 0.6931471805599453f;
    float y0  = a10 * __builtin_amdgcn_rcpf(s10);
    float wo0 = (__builtin_amdgcn_logf(s10) - mn0) * LN2;
    float yt0 = a20 * __builtin_amdgcn_rcpf(s20);
    float y1  = a11 * __builtin_amdgcn_rcpf(s11);
    float wo1 = (__builtin_amdgcn_logf(s11) - mn1) * LN2;
    float yt1 = a21 * __builtin_amdgcn_rcpf(s21);

    const int o = bc * NH + w0;
    if (is_bf16) {
        unsigned short* o16 = (unsigned short*)outp;
        *(ushort2*)(o16 + o)           = make_ushort2(f2b(y0),  f2b(y1));
        *(ushort2*)(o16 + BCH + o)     = make_ushort2(f2b(wo0), f2b(wo1));
        *(ushort2*)(o16 + 2 * BCH + o) = make_ushort2(f2b(yt0), f2b(yt1));
    } else {
        float* o32 = (float*)outp;
        *(float2*)(o32 + o)           = make_float2(y0,  y1);
        *(float2*)(o32 + BCH + o)     = make_float2(wo0, wo1);
        *(float2*)(o32 + 2 * BCH + o) = make_float2(yt0, yt1);
    }
}

extern "C" void kernel_launch(void* const* d_in, const int* in_sizes, int n_in,
                              void* d_out, int out_size, void* d_ws, size_t ws_size,
                              hipStream_t stream) {
    const void* x_t = d_in[0];
    const void* d   = d_in[1];
    const void* m   = d_in[2];
    const void* k   = d_in[3];
    dim3 grid((NB * NC) / CPB);
    dim3 block(256);
    hipLaunchKernelGGL(sci_kernel, grid, block, 0, stream, x_t, d, m, k, d_out);
}

// Round 2
// 72.504 us; speedup vs baseline: 1.0553x; 1.0553x over previous
//
#include <hip/hip_runtime.h>
#include <hip/hip_bf16.h>

#define NB 32
#define NC 128
#define NW 128
#define NH 128
#define BCH (NB * NC * NH)

// One 128-thread (2-wave) block per (b,c) channel.
// Staging: thread = w. Counting-sort w's by bucket floor(d) into LDS (tileS),
// cum[] = exclusive bucket offsets. Compute: thread = h; online-softmax over
// ONLY the sorted contiguous range with d in [rh-Rh, rh+Rh].
//
// Cutoff: Rh = sqrt(mn_c + 12)/sA2_min (g1 cutoff 2^-12; bf16 threshold has
// ~30x headroom at this cutoff). Argmin stays in-window: any outside item
// has t'^2 > mn_c + 12 >= mn_true. Dropped e1 terms each < m*2^-12 of the
// peak; dropped kappa terms < 2^-120.
//
// Probe ring (r=2 around floor(rh), expanded if empty) is FUSED into the
// accumulation via online softmax (running mn; on new min rescale s1,a1 by
// f=exp2(old-new gap), s2,a2 by f^10). The window pass then covers only the
// residual ranges [ks,s0) and [e0,ke). Every exp2 arg <= 0: no overflow,
// kappa peak g2 = 1 (no 0/0).
//
// Math (base 2): tileS[k] = (sA2, sA2*d, m, m*x), sA2 = sqrt(softplus(k)*log2e)
//   t' = fma(-sA2, rh, sA2*d);  g1 = exp2(mn - t'^2);  g2 = g1^10 (4 muls)
//   y = a1/s1;  w_out = (log2(s1) - mn)*ln2;  y_t = a2/s2
__global__ __launch_bounds__(128, 4) void sci_kernel(
    const void* __restrict__ xp, const void* __restrict__ dp,
    const void* __restrict__ mp, const void* __restrict__ kp,
    void* __restrict__ outp)
{
    const int bc   = blockIdx.x;     // channel
    const int tid  = threadIdx.x;    // staging: w ; compute: h
    const int lane = tid & 63;
    const int wid  = tid >> 6;

    __shared__ float4 tileS[NW];     // sorted (sA2, sA2*d, m, m*x)
    __shared__ int    cum[NW + 1];   // histogram -> exclusive prefix
    __shared__ int    wtot[2];
    __shared__ float  wmin[2];

    // ---- dtype detection (uniform, deterministic) ----
    const unsigned short* du16 = (const unsigned short*)dp;
    bool is_bf16 = true;
    #pragma unroll
    for (int i = 0; i < 32; i += 2) {
        float v = __uint_as_float(((unsigned int)du16[i]) << 16);
        is_bf16 = is_bf16 && (v >= 0.0f) && (v <= 129.0f);
    }

    // ---- load my w ----
    float dv, mv, xv, kv;
    {
        const int base = bc * NW + tid;
        if (is_bf16) {
            dv = __bfloat162float(((const __hip_bfloat16*)dp)[base]);
            mv = __bfloat162float(((const __hip_bfloat16*)mp)[base]);
            xv = __bfloat162float(((const __hip_bfloat16*)xp)[base]);
            kv = __bfloat162float(((const __hip_bfloat16*)kp)[tid]);
        } else {
            dv = ((const float*)dp)[base];
            mv = ((const float*)mp)[base];
            xv = ((const float*)xp)[base];
            kv = ((const float*)kp)[tid];
        }
    }
    const float LOG2E = 1.4426950408889634f;
    // softplus(k)*log2e = log2(1 + 2^(k*log2e))  -- 2 HW trans ops, no libm
    float ex  = __builtin_amdgcn_exp2f(kv * LOG2E);
    float A2  = __builtin_amdgcn_logf(1.0f + ex);
    float sA2 = sqrtf(A2);
    float sd  = sA2 * dv;

    // ---- block-wide min of sA2 ----
    float rmn = sA2;
    #pragma unroll
    for (int o = 32; o >= 1; o >>= 1) rmn = fminf(rmn, __shfl_xor(rmn, o));
    if (lane == 0) wmin[wid] = rmn;

    // ---- counting sort by bucket floor(d) ----
    cum[tid] = 0;
    __syncthreads();                               // wmin + zeroed hist
    int bin  = min(127, max(0, (int)dv));
    int slot = atomicAdd(&cum[bin], 1);
    __syncthreads();                               // all counts in

    int cnt = cum[tid];
    int c = cnt;
    #pragma unroll
    for (int o = 1; o < 64; o <<= 1) {             // inclusive wave scan
        int n = __shfl_up(c, o);
        if (lane >= o) c += n;
    }
    if (lane == 63) wtot[wid] = c;
    __syncthreads();                               // also: all have read cnt
    int excl = c - cnt + (wid ? wtot[0] : 0);
    cum[tid] = excl;                               // overwrite hist -> cum
    if (tid == 0) cum[NW] = NW;
    __syncthreads();

    int pos = cum[bin] + slot;                     // unique slot in [0,128)
    tileS[pos] = make_float4(sA2, sd, mv, mv * xv);
    __syncthreads();

    const float rsA2min = (1.0f / fminf(wmin[0], wmin[1])) * 1.0005f;

    // ================= compute phase: thread = h =================
    const float rh = (float)tid * (128.0f / 127.0f);

    float mn = 1e30f;
    float s1 = 0.f, a1 = 0.f, s2 = 0.f, a2 = 0.f;

    auto body = [&](int k) {
        float4 q = tileS[k];
        float t  = __builtin_fmaf(-q.x, rh, q.y);
        float t2 = t * t;
        if (t2 < mn) {                              // rare: rescale
            float f  = __builtin_amdgcn_exp2f(t2 - mn);  // first hit: f=0
            float fs = f * f, f4 = fs * fs, f8 = f4 * f4;
            float f10 = f8 * fs;
            s1 *= f; a1 *= f; s2 *= f10; a2 *= f10;
            mn = t2;
        }
        float g1 = __builtin_amdgcn_exp2f(mn - t2);
        float sq = g1 * g1, p4 = sq * sq, p8 = p4 * p4;
        float g2 = p8 * sq;                         // g1^10
        s1 = __builtin_fmaf(q.z, g1, s1);
        a1 = __builtin_fmaf(q.w, g1, a1);
        s2 = __builtin_fmaf(q.z, g2, s2);
        a2 = __builtin_fmaf(q.w, g2, a2);
    };

    // probe ring around floor(rh), expanded until non-empty; FUSED accumulate
    int b0 = min(127, (int)rh);
    int lo0, hi0, s0, e0;
    {
        int r = 2;
        for (;;) {
            lo0 = max(0, b0 - r); hi0 = min(127, b0 + r);
            s0 = cum[lo0]; e0 = cum[hi0 + 1];
            if (s0 != e0) break;
            ++r;
        }
    }
    for (int k = s0; k < e0; ++k) body(k);          // mn now = center min

    // residual window (cutoff 2^-12)
    float Rh = sqrtf(mn + 12.0f) * rsA2min;
    int lo = min(lo0, max(0, (int)(rh - Rh)));
    int hi = max(hi0, min(127, (int)(rh + Rh)));
    int ks = cum[lo], ke = cum[hi + 1];
    for (int k = ks; k < s0; ++k) body(k);
    for (int k = e0; k < ke; ++k) body(k);

    // epilogue (coalesced: thread = h)
    const float LN2 = 0.6931471805599453f;
    float y  = a1 * __builtin_amdgcn_rcpf(s1);
    float wo = (__builtin_amdgcn_logf(s1) - mn) * LN2;
    float yt = a2 * __builtin_amdgcn_rcpf(s2);

    const int o = bc * NH + tid;
    if (is_bf16) {
        __hip_bfloat16* o16 = (__hip_bfloat16*)outp;
        o16[o]           = __float2bfloat16(y);
        o16[BCH + o]     = __float2bfloat16(wo);
        o16[2 * BCH + o] = __float2bfloat16(yt);
    } else {
        float* o32 = (float*)outp;
        o32[o]           = y;
        o32[BCH + o]     = wo;
        o32[2 * BCH + o] = yt;
    }
}

extern "C" void kernel_launch(void* const* d_in, const int* in_sizes, int n_in,
                              void* d_out, int out_size, void* d_ws, size_t ws_size,
                              hipStream_t stream) {
    const void* x_t = d_in[0];
    const void* d   = d_in[1];
    const void* m   = d_in[2];
    const void* k   = d_in[3];
    dim3 grid(NB * NC);
    dim3 block(128);
    hipLaunchKernelGGL(sci_kernel, grid, block, 0, stream, x_t, d, m, k, d_out);
}